// Round 15
// baseline (200.124 us; speedup 1.0000x reference)
//
#include <hip/hip_runtime.h>
#include <stdint.h>

#define IN_D  4096
#define OUT_D 4096
#define BATCH 4096
#define NEG_SLOPE 0.1f
#define NSEG 8       // counter/bucket split (XCD-aligned via blockIdx&7)
#define SEGCAP 192   // per-(col,seg) capacity; mean 51, 20 sigma headroom

typedef __attribute__((ext_vector_type(8))) short short8;
typedef __attribute__((ext_vector_type(4))) float f32x4;

// ---------- helpers ----------
__device__ __forceinline__ unsigned short f2bf(float f) {
    unsigned u = __builtin_bit_cast(unsigned, f);
    u += 0x7FFFu + ((u >> 16) & 1u);
    return (unsigned short)(u >> 16);
}

__device__ __forceinline__ void gload_lds16(const unsigned short* gsrc, unsigned short* ldsp) {
    __builtin_amdgcn_global_load_lds(
        (const __attribute__((address_space(1))) unsigned int*)gsrc,
        (__attribute__((address_space(3))) unsigned int*)ldsp,
        16, 0, 0);
}

// ---------- prep K2: bucket scatter + x->bf16 cvt ----------
// entry: .x = row | (bf16(w) << 16), .y = i+1  (winner = max .y per row)
__global__ void bucketcvt_kernel(const int* __restrict__ rows, const int* __restrict__ cols,
                                 const float* __restrict__ w,
                                 unsigned* __restrict__ cnt, uint2* __restrict__ bucket,
                                 int nnz,
                                 const float4* __restrict__ x, ushort4* __restrict__ xb,
                                 int nx4) {
    const int stride = gridDim.x * blockDim.x;
    const int i0 = blockIdx.x * blockDim.x + threadIdx.x;
    const int g = blockIdx.x & (NSEG - 1);
    for (int i = i0; i < nnz; i += stride) {
        int c = cols[i];
        unsigned pos = atomicAdd(&cnt[g * OUT_D + c], 1u);
        if (pos < SEGCAP)
            bucket[((size_t)g * OUT_D + c) * SEGCAP + pos] =
                make_uint2((unsigned)rows[i] | ((unsigned)f2bf(w[i]) << 16),
                           (unsigned)(i + 1));
    }
    for (int i = i0; i < nx4; i += stride) {
        float4 v = x[i];
        ushort4 o;
        o.x = f2bf(v.x); o.y = f2bf(v.y); o.z = f2bf(v.z); o.w = f2bf(v.w);
        xb[i] = o;
    }
}

// ---------- prep K3: per-column single-pass u64 LDS dedup + dense write ----------
__global__ __launch_bounds__(256) void coldedup_kernel(
        const uint2* __restrict__ bucket, const unsigned* __restrict__ cnt,
        unsigned short* __restrict__ Wt) {
    __shared__ unsigned long long tag[IN_D];   // 32 KB
    const int col = blockIdx.x;
    const int tid = threadIdx.x;

    uint4* t4 = (uint4*)tag;                   // 2048 uint4
    #pragma unroll
    for (int j = 0; j < 8; ++j) t4[tid + j * 256] = make_uint4(0u, 0u, 0u, 0u);
    __syncthreads();

    #pragma unroll
    for (int g = 0; g < NSEG; ++g) {
        const int n = min((int)cnt[g * OUT_D + col], SEGCAP);
        const uint2* bk = bucket + ((size_t)g * OUT_D + col) * SEGCAP;
        for (int e = tid; e < n; e += 256) {
            uint2 u = bk[e];
            unsigned long long v = ((unsigned long long)u.y << 16) | (u.x >> 16);
            atomicMax(&tag[u.x & 0xFFFu], v);
        }
    }
    __syncthreads();

    const int r0 = tid * 16;
    short8 o0, o1;
    #pragma unroll
    for (int j = 0; j < 8; ++j) {
        o0[j] = (short)(unsigned short)(tag[r0 + j] & 0xFFFFu);
        o1[j] = (short)(unsigned short)(tag[r0 + 8 + j] & 0xFFFFu);
    }
    *(short8*)&Wt[(size_t)col * IN_D + r0]     = o0;
    *(short8*)&Wt[(size_t)col * IN_D + r0 + 8] = o1;
}

// ---------- GEMM: 256x256 tile, BK=64, 8 waves, split-shadow schedule ----------
#define BM 256
#define BN 256
#define BK 64
#define NT (IN_D / BK)   // 64 K-tiles

#define QUAD(MI0, NI0, AREG, BREG) \
    _Pragma("unroll") \
    for (int mi = 0; mi < 4; ++mi) { \
      _Pragma("unroll") \
      for (int ni = 0; ni < 2; ++ni) { \
        _Pragma("unroll") \
        for (int ks = 0; ks < 2; ++ks) { \
          acc[(MI0)+mi][(NI0)+ni] = __builtin_amdgcn_mfma_f32_16x16x32_bf16( \
              AREG[mi][ks], BREG[ni][ks], acc[(MI0)+mi][(NI0)+ni], 0, 0, 0); \
        } } }

#define PHASE_TAIL(QUADCALL) \
    __builtin_amdgcn_s_barrier(); \
    asm volatile("s_waitcnt lgkmcnt(0)" ::: "memory"); \
    __builtin_amdgcn_sched_barrier(0); \
    __builtin_amdgcn_s_setprio(1); \
    QUADCALL; \
    __builtin_amdgcn_s_setprio(0); \
    __builtin_amdgcn_s_barrier();

// early shadow group: A-h0 (8 -> a) + B-h1 (4 -> b1) — no WAR vs QUAD(4,0)
#define PREFETCH_A_B1(D) \
    _Pragma("unroll") \
    for (int mi = 0; mi < 4; ++mi) { \
        a[mi][0] = *(const short8*)&lds[D][0][0][(jA_base + mi * 16) * 64 + kp0]; \
        a[mi][1] = *(const short8*)&lds[D][0][0][(jA_base + mi * 16) * 64 + kp1]; \
    } \
    b1[0][0] = *(const short8*)&lds[D][1][1][jB[2] * 64 + kp0]; \
    b1[0][1] = *(const short8*)&lds[D][1][1][jB[2] * 64 + kp1]; \
    b1[1][0] = *(const short8*)&lds[D][1][1][jB[3] * 64 + kp0]; \
    b1[1][1] = *(const short8*)&lds[D][1][1][jB[3] * 64 + kp1];

// late shadow group: B-h0 (4 -> b0) + A-h1 (8 -> a2) — WAR: after QUAD(4,0)
#define PREFETCH_B0_A2(D) \
    b0[0][0] = *(const short8*)&lds[D][1][0][jB[0] * 64 + kp0]; \
    b0[0][1] = *(const short8*)&lds[D][1][0][jB[0] * 64 + kp1]; \
    b0[1][0] = *(const short8*)&lds[D][1][0][jB[1] * 64 + kp0]; \
    b0[1][1] = *(const short8*)&lds[D][1][0][jB[1] * 64 + kp1]; \
    _Pragma("unroll") \
    for (int mi = 0; mi < 4; ++mi) { \
        a2[mi][0] = *(const short8*)&lds[D][0][1][(jA_base + mi * 16) * 64 + kp0]; \
        a2[mi][1] = *(const short8*)&lds[D][0][1][(jA_base + mi * 16) * 64 + kp1]; \
    }

__global__ __launch_bounds__(512) void gemm_kernel(
        const unsigned short* __restrict__ Xb,   // [BATCH][IN_D] bf16
        const unsigned short* __restrict__ Wt,   // [OUT_D][IN_D] bf16
        const float* __restrict__ bias,
        float* __restrict__ out)                 // [BATCH][OUT_D] fp32
{
    // [dbuf][side A=0/B=1][half][j*64 + k]   (128 KiB)
    __shared__ unsigned short lds[2][2][2][128 * 64];

    const int tid  = threadIdx.x;
    const int lane = tid & 63;
    const int wave = tid >> 6;

    // bijective XCD swizzle (nwg=256, 8 XCDs, 256%8==0)
    const int lin = blockIdx.y * 16 + blockIdx.x;
    const int swz = (lin & 7) * 32 + (lin >> 3);
    const int m0 = (swz >> 4) * BM;
    const int n0 = (swz & 15) * BN;

    const int wm = (wave >> 2) * 128;
    const int wn = (wave & 3) * 64;

    const int lr = lane & 15;
    const int kg = lane >> 4;
    const int x7 = lr & 7;
    const int l8 = lane >> 3;
    const int c8 = lane & 7;

    // swizzled physical k-elem offsets (bank-conflict-free; measured 0 conflicts)
    const int kp0 = ((0 * 4 + kg) ^ x7) * 8;
    const int kp1 = ((1 * 4 + kg) ^ x7) * 8;

    const int jA_base = (wave >> 2) * 64 + lr;
    int jB[4];
    #pragma unroll
    for (int ni = 0; ni < 4; ++ni) {
        int r16 = wn + ni * 16;
        jB[ni] = (r16 & 31) + ((r16 >> 6) << 5) + lr;
    }

    auto stageA = [&](int d, int h, int kt) {
        #pragma unroll
        for (int s = 0; s < 2; ++s) {
            int j = wave * 16 + s * 8 + l8;
            int trow = (j & 63) + h * 64 + ((j >> 6) << 7);
            const unsigned short* src =
                Xb + (size_t)(m0 + trow) * IN_D + kt * BK + 8 * (c8 ^ l8);
            gload_lds16(src, &lds[d][0][h][(wave * 16 + s * 8) * 64]);
        }
    };
    auto stageB = [&](int d, int h, int kt) {
        #pragma unroll
        for (int s = 0; s < 2; ++s) {
            int j = wave * 16 + s * 8 + l8;
            int trow = (j & 31) + h * 32 + ((j >> 5) << 6);
            const unsigned short* src =
                Wt + (size_t)(n0 + trow) * IN_D + kt * BK + 8 * (c8 ^ l8);
            gload_lds16(src, &lds[d][1][h][(wave * 16 + s * 8) * 64]);
        }
    };

    f32x4 acc[8][4] = {};
    short8 a[4][2], a2[4][2], b0[2][2], b1[2][2];

    // prologue: tile0 all 4 halves -> buf0 (first 8 loads); tile1 -> buf1
    stageA(0, 0, 0); stageB(0, 0, 0); stageB(0, 1, 0); stageA(0, 1, 0);
    stageA(1, 0, 1); stageB(1, 1, 1); stageA(1, 1, 1); stageB(1, 0, 1);
    asm volatile("s_waitcnt vmcnt(8)" ::: "memory");   // tile0 fully landed
    __builtin_amdgcn_s_barrier();
    // peeled P1(tile 0): full prefetch + first quadrant
    PREFETCH_A_B1(0)
    PREFETCH_B0_A2(0)
    asm volatile("s_waitcnt lgkmcnt(0)" ::: "memory");
    __builtin_amdgcn_sched_barrier(0);
    __builtin_amdgcn_s_setprio(1);
    QUAD(0, 0, a, b0)
    __builtin_amdgcn_s_setprio(0);
    __builtin_amdgcn_s_barrier();

    for (int t = 0; t < NT - 1; ++t) {
        const int cur = t & 1, nxt = cur ^ 1;
        const int kt2 = (t + 2) & (NT - 1);

        // P2: no ds_reads; stage A-h0(t+2) -> cur
        stageA(cur, 0, kt2);
        PHASE_TAIL(QUAD(0, 2, a, b1))

        // P3: no ds_reads (a2 prefetched); stage B-h1(t+2) -> cur
        stageB(cur, 1, kt2);
        PHASE_TAIL(QUAD(4, 2, a2, b1))

        // M = P4 + P1(t+1), single barrier pair, SPLIT shadow:
        //   stage A-h1(t+2); vmcnt(6) => tile t+1 fully landed in nxt;
        //   early reads a/b1(t+1) (no WAR) -> complete under QUAD(4,0);
        //   QUAD(4,0); late reads b0/a2(t+1) (WAR-ordered) + stage B-h0(t+2);
        //   lgkm; QUAD(0,0) of tile t+1.
        stageA(cur, 1, kt2);
        asm volatile("s_waitcnt vmcnt(6)" ::: "memory");
        __builtin_amdgcn_s_barrier();
        asm volatile("s_waitcnt lgkmcnt(0)" ::: "memory");
        __builtin_amdgcn_sched_barrier(0);
        PREFETCH_A_B1(nxt)
        __builtin_amdgcn_sched_barrier(0);   // pin early reads before MFMA cluster
        __builtin_amdgcn_s_setprio(1);
        QUAD(4, 0, a2, b0)
        __builtin_amdgcn_s_setprio(0);
        PREFETCH_B0_A2(nxt)
        stageB(cur, 0, kt2);
        asm volatile("s_waitcnt lgkmcnt(0)" ::: "memory");
        __builtin_amdgcn_sched_barrier(0);
        __builtin_amdgcn_s_setprio(1);
        QUAD(0, 0, a, b0)
        __builtin_amdgcn_s_setprio(0);
        __builtin_amdgcn_s_barrier();
    }

    // tail: t = NT-1 — everything already in registers, zero ds_reads
    {
        __builtin_amdgcn_s_setprio(1);
        QUAD(0, 2, a, b1)
        QUAD(4, 2, a2, b1)
        QUAD(4, 0, a2, b0)
        __builtin_amdgcn_s_setprio(0);
    }

    // epilogue: bias + leaky_relu, fp32 store
    float bfrag[4];
    #pragma unroll
    for (int ni = 0; ni < 4; ++ni) bfrag[ni] = bias[n0 + wn + ni * 16 + lr];

    #pragma unroll
    for (int mi = 0; mi < 8; ++mi) {
        #pragma unroll
        for (int ni = 0; ni < 4; ++ni) {
            const int col = n0 + wn + ni * 16 + lr;
            #pragma unroll
            for (int r = 0; r < 4; ++r) {
                const int row = m0 + wm + mi * 16 + kg * 4 + r;
                float v = acc[mi][ni][r] + bfrag[ni];
                v = v > 0.0f ? v : v * NEG_SLOPE;
                out[(size_t)row * OUT_D + col] = v;
            }
        }
    }
}

// ---------- launch ----------
extern "C" void kernel_launch(void* const* d_in, const int* in_sizes, int n_in,
                              void* d_out, int out_size, void* d_ws, size_t ws_size,
                              hipStream_t stream) {
    const float* x    = (const float*)d_in[0];
    const float* w    = (const float*)d_in[1];
    const float* bias = (const float*)d_in[2];
    const int*   rows = (const int*)d_in[3];
    const int*   cols = (const int*)d_in[4];
    const int nnz = in_sizes[1];
    float* out = (float*)d_out;

    const size_t NW = (size_t)IN_D * OUT_D;
    // ws: cnt 128 KB (pad 1 MiB) | bucket 48 MiB | Wt 32 MiB | Xb 32 MiB = 113 MiB
    unsigned*        cnt    = (unsigned*)d_ws;
    uint2*           bucket = (uint2*)((char*)d_ws + (1u << 20));
    unsigned short*  Wt     = (unsigned short*)((char*)d_ws + (1u << 20)
                                  + (size_t)NSEG * OUT_D * SEGCAP * 8);
    unsigned short*  Xb     = (unsigned short*)((char*)Wt + NW * 2);

    hipMemsetAsync(cnt, 0, (size_t)NSEG * OUT_D * sizeof(unsigned), stream);
    bucketcvt_kernel<<<4096, 256, 0, stream>>>(rows, cols, w, cnt, bucket, nnz,
                                               (const float4*)x, (ushort4*)Xb,
                                               (int)((size_t)BATCH * IN_D / 4));
    coldedup_kernel<<<OUT_D, 256, 0, stream>>>(bucket, cnt, Wt);

    dim3 grid(OUT_D / BN, BATCH / BM);
    gemm_kernel<<<grid, 512, 0, stream>>>(Xb, Wt, bias, out);
}

// Round 16
// 197.673 us; speedup vs baseline: 1.0124x; 1.0124x over previous
//
#include <hip/hip_runtime.h>
#include <stdint.h>

#define IN_D  4096
#define OUT_D 4096
#define BATCH 4096
#define NEG_SLOPE 0.1f
#define NSEG 8       // counter/bucket split (XCD-aligned via blockIdx&7)
#define SEGCAP 192   // per-(col,seg) capacity; mean 51, 20 sigma headroom

typedef __attribute__((ext_vector_type(8))) short short8;
typedef __attribute__((ext_vector_type(4))) float f32x4;

// ---------- helpers ----------
__device__ __forceinline__ unsigned short f2bf(float f) {
    unsigned u = __builtin_bit_cast(unsigned, f);
    u += 0x7FFFu + ((u >> 16) & 1u);
    return (unsigned short)(u >> 16);
}

__device__ __forceinline__ void gload_lds16(const unsigned short* gsrc, unsigned short* ldsp) {
    __builtin_amdgcn_global_load_lds(
        (const __attribute__((address_space(1))) unsigned int*)gsrc,
        (__attribute__((address_space(3))) unsigned int*)ldsp,
        16, 0, 0);
}

// ---------- prep K2: bucket scatter + x->bf16 cvt ----------
// entry: .x = row | (bf16(w) << 16), .y = i+1  (winner = max .y per row)
__global__ void bucketcvt_kernel(const int* __restrict__ rows, const int* __restrict__ cols,
                                 const float* __restrict__ w,
                                 unsigned* __restrict__ cnt, uint2* __restrict__ bucket,
                                 int nnz,
                                 const float4* __restrict__ x, ushort4* __restrict__ xb,
                                 int nx4) {
    const int stride = gridDim.x * blockDim.x;
    const int i0 = blockIdx.x * blockDim.x + threadIdx.x;
    const int g = blockIdx.x & (NSEG - 1);
    for (int i = i0; i < nnz; i += stride) {
        int c = cols[i];
        unsigned pos = atomicAdd(&cnt[g * OUT_D + c], 1u);
        if (pos < SEGCAP)
            bucket[((size_t)g * OUT_D + c) * SEGCAP + pos] =
                make_uint2((unsigned)rows[i] | ((unsigned)f2bf(w[i]) << 16),
                           (unsigned)(i + 1));
    }
    for (int i = i0; i < nx4; i += stride) {
        float4 v = x[i];
        ushort4 o;
        o.x = f2bf(v.x); o.y = f2bf(v.y); o.z = f2bf(v.z); o.w = f2bf(v.w);
        xb[i] = o;
    }
}

// ---------- prep K3: per-column single-pass u64 LDS dedup + dense write ----------
__global__ __launch_bounds__(256) void coldedup_kernel(
        const uint2* __restrict__ bucket, const unsigned* __restrict__ cnt,
        unsigned short* __restrict__ Wt) {
    __shared__ unsigned long long tag[IN_D];   // 32 KB
    const int col = blockIdx.x;
    const int tid = threadIdx.x;

    uint4* t4 = (uint4*)tag;                   // 2048 uint4
    #pragma unroll
    for (int j = 0; j < 8; ++j) t4[tid + j * 256] = make_uint4(0u, 0u, 0u, 0u);
    __syncthreads();

    #pragma unroll
    for (int g = 0; g < NSEG; ++g) {
        const int n = min((int)cnt[g * OUT_D + col], SEGCAP);
        const uint2* bk = bucket + ((size_t)g * OUT_D + col) * SEGCAP;
        for (int e = tid; e < n; e += 256) {
            uint2 u = bk[e];
            unsigned long long v = ((unsigned long long)u.y << 16) | (u.x >> 16);
            atomicMax(&tag[u.x & 0xFFFu], v);
        }
    }
    __syncthreads();

    const int r0 = tid * 16;
    short8 o0, o1;
    #pragma unroll
    for (int j = 0; j < 8; ++j) {
        o0[j] = (short)(unsigned short)(tag[r0 + j] & 0xFFFFu);
        o1[j] = (short)(unsigned short)(tag[r0 + 8 + j] & 0xFFFFu);
    }
    *(short8*)&Wt[(size_t)col * IN_D + r0]     = o0;
    *(short8*)&Wt[(size_t)col * IN_D + r0 + 8] = o1;
}

// ---------- GEMM: 256x256 tile, BK=64, 8 waves, full-shadow-prefetch schedule ----------
#define BM 256
#define BN 256
#define BK 64
#define NT (IN_D / BK)   // 64 K-tiles

#define QUAD(MI0, NI0, AREG, BREG) \
    _Pragma("unroll") \
    for (int mi = 0; mi < 4; ++mi) { \
      _Pragma("unroll") \
      for (int ni = 0; ni < 2; ++ni) { \
        _Pragma("unroll") \
        for (int ks = 0; ks < 2; ++ks) { \
          acc[(MI0)+mi][(NI0)+ni] = __builtin_amdgcn_mfma_f32_16x16x32_bf16( \
              AREG[mi][ks], BREG[ni][ks], acc[(MI0)+mi][(NI0)+ni], 0, 0, 0); \
        } } }

#define PHASE_TAIL(QUADCALL) \
    __builtin_amdgcn_s_barrier(); \
    asm volatile("s_waitcnt lgkmcnt(0)" ::: "memory"); \
    __builtin_amdgcn_sched_barrier(0); \
    __builtin_amdgcn_s_setprio(1); \
    QUADCALL; \
    __builtin_amdgcn_s_setprio(0); \
    __builtin_amdgcn_s_barrier();

// 24 reads: A-h0 (8 -> a) + B-h0 (4 -> b0) + B-h1 (4 -> b1) + A-h1 (8 -> a2)
#define PREFETCH4(D) \
    _Pragma("unroll") \
    for (int mi = 0; mi < 4; ++mi) { \
        a[mi][0] = *(const short8*)&lds[D][0][0][(jA_base + mi * 16) * 64 + kp0]; \
        a[mi][1] = *(const short8*)&lds[D][0][0][(jA_base + mi * 16) * 64 + kp1]; \
    } \
    b0[0][0] = *(const short8*)&lds[D][1][0][jB[0] * 64 + kp0]; \
    b0[0][1] = *(const short8*)&lds[D][1][0][jB[0] * 64 + kp1]; \
    b0[1][0] = *(const short8*)&lds[D][1][0][jB[1] * 64 + kp0]; \
    b0[1][1] = *(const short8*)&lds[D][1][0][jB[1] * 64 + kp1]; \
    b1[0][0] = *(const short8*)&lds[D][1][1][jB[2] * 64 + kp0]; \
    b1[0][1] = *(const short8*)&lds[D][1][1][jB[2] * 64 + kp1]; \
    b1[1][0] = *(const short8*)&lds[D][1][1][jB[3] * 64 + kp0]; \
    b1[1][1] = *(const short8*)&lds[D][1][1][jB[3] * 64 + kp1]; \
    _Pragma("unroll") \
    for (int mi = 0; mi < 4; ++mi) { \
        a2[mi][0] = *(const short8*)&lds[D][0][1][(jA_base + mi * 16) * 64 + kp0]; \
        a2[mi][1] = *(const short8*)&lds[D][0][1][(jA_base + mi * 16) * 64 + kp1]; \
    }

__global__ __launch_bounds__(512) void gemm_kernel(
        const unsigned short* __restrict__ Xb,   // [BATCH][IN_D] bf16
        const unsigned short* __restrict__ Wt,   // [OUT_D][IN_D] bf16
        const float* __restrict__ bias,
        float* __restrict__ out)                 // [BATCH][OUT_D] fp32
{
    // [dbuf][side A=0/B=1][half][j*64 + k]   (128 KiB)
    __shared__ unsigned short lds[2][2][2][128 * 64];

    const int tid  = threadIdx.x;
    const int lane = tid & 63;
    const int wave = tid >> 6;

    // bijective XCD swizzle (nwg=256, 8 XCDs, 256%8==0)
    const int lin = blockIdx.y * 16 + blockIdx.x;
    const int swz = (lin & 7) * 32 + (lin >> 3);
    const int m0 = (swz >> 4) * BM;
    const int n0 = (swz & 15) * BN;

    const int wm = (wave >> 2) * 128;
    const int wn = (wave & 3) * 64;

    const int lr = lane & 15;
    const int kg = lane >> 4;
    const int x7 = lr & 7;
    const int l8 = lane >> 3;
    const int c8 = lane & 7;

    // swizzled physical k-elem offsets (bank-conflict-free; measured 0 conflicts)
    const int kp0 = ((0 * 4 + kg) ^ x7) * 8;
    const int kp1 = ((1 * 4 + kg) ^ x7) * 8;

    const int jA_base = (wave >> 2) * 64 + lr;
    int jB[4];
    #pragma unroll
    for (int ni = 0; ni < 4; ++ni) {
        int r16 = wn + ni * 16;
        jB[ni] = (r16 & 31) + ((r16 >> 6) << 5) + lr;
    }

    auto stageA = [&](int d, int h, int kt) {
        #pragma unroll
        for (int s = 0; s < 2; ++s) {
            int j = wave * 16 + s * 8 + l8;
            int trow = (j & 63) + h * 64 + ((j >> 6) << 7);
            const unsigned short* src =
                Xb + (size_t)(m0 + trow) * IN_D + kt * BK + 8 * (c8 ^ l8);
            gload_lds16(src, &lds[d][0][h][(wave * 16 + s * 8) * 64]);
        }
    };
    auto stageB = [&](int d, int h, int kt) {
        #pragma unroll
        for (int s = 0; s < 2; ++s) {
            int j = wave * 16 + s * 8 + l8;
            int trow = (j & 31) + h * 32 + ((j >> 5) << 6);
            const unsigned short* src =
                Wt + (size_t)(n0 + trow) * IN_D + kt * BK + 8 * (c8 ^ l8);
            gload_lds16(src, &lds[d][1][h][(wave * 16 + s * 8) * 64]);
        }
    };

    f32x4 acc[8][4] = {};
    short8 a[4][2], a2[4][2], b0[2][2], b1[2][2];

    // prologue: tile0 all 4 halves -> buf0 (first 8 loads); tile1 -> buf1
    stageA(0, 0, 0); stageB(0, 0, 0); stageB(0, 1, 0); stageA(0, 1, 0);
    stageA(1, 0, 1); stageB(1, 1, 1); stageA(1, 1, 1); stageB(1, 0, 1);
    asm volatile("s_waitcnt vmcnt(8)" ::: "memory");   // tile0 fully landed
    __builtin_amdgcn_s_barrier();
    // peeled P1(tile 0): full prefetch + first quadrant
    PREFETCH4(0)
    asm volatile("s_waitcnt lgkmcnt(0)" ::: "memory");
    __builtin_amdgcn_sched_barrier(0);
    __builtin_amdgcn_s_setprio(1);
    QUAD(0, 0, a, b0)
    __builtin_amdgcn_s_setprio(0);
    __builtin_amdgcn_s_barrier();

    for (int t = 0; t < NT - 1; ++t) {
        const int cur = t & 1, nxt = cur ^ 1;
        const int kt2 = (t + 2) & (NT - 1);

        // P2: no ds_reads; stage A-h0(t+2) -> cur
        stageA(cur, 0, kt2);
        PHASE_TAIL(QUAD(0, 2, a, b1))

        // P3: no ds_reads (a2 prefetched); stage B-h1(t+2) -> cur
        stageB(cur, 1, kt2);
        PHASE_TAIL(QUAD(4, 2, a2, b1))

        // M = P4 + P1(t+1), single barrier pair:
        //   stage A-h1(t+2); vmcnt(6) => tile t+1 fully landed in nxt
        //   (incl. A-h1(t+1)/B-h0(t+1) staged at M(t-1): pre-P2(t) issue);
        //   QUAD(4,0); full prefetch of tile t+1 in MFMA shadow;
        //   stage B-h0(t+2) -> cur; QUAD(0,0) for tile t+1.
        stageA(cur, 1, kt2);
        asm volatile("s_waitcnt vmcnt(6)" ::: "memory");
        __builtin_amdgcn_s_barrier();
        asm volatile("s_waitcnt lgkmcnt(0)" ::: "memory");
        __builtin_amdgcn_sched_barrier(0);
        __builtin_amdgcn_s_setprio(1);
        QUAD(4, 0, a2, b0)
        __builtin_amdgcn_s_setprio(0);
        PREFETCH4(nxt)
        stageB(cur, 0, kt2);
        asm volatile("s_waitcnt lgkmcnt(0)" ::: "memory");
        __builtin_amdgcn_sched_barrier(0);
        __builtin_amdgcn_s_setprio(1);
        QUAD(0, 0, a, b0)
        __builtin_amdgcn_s_setprio(0);
        __builtin_amdgcn_s_barrier();
    }

    // tail: t = NT-1 — everything already in registers, zero ds_reads
    {
        __builtin_amdgcn_s_setprio(1);
        QUAD(0, 2, a, b1)
        QUAD(4, 2, a2, b1)
        QUAD(4, 0, a2, b0)
        __builtin_amdgcn_s_setprio(0);
    }

    // epilogue: bias + leaky_relu, fp32 store
    float bfrag[4];
    #pragma unroll
    for (int ni = 0; ni < 4; ++ni) bfrag[ni] = bias[n0 + wn + ni * 16 + lr];

    #pragma unroll
    for (int mi = 0; mi < 8; ++mi) {
        #pragma unroll
        for (int ni = 0; ni < 4; ++ni) {
            const int col = n0 + wn + ni * 16 + lr;
            #pragma unroll
            for (int r = 0; r < 4; ++r) {
                const int row = m0 + wm + mi * 16 + kg * 4 + r;
                float v = acc[mi][ni][r] + bfrag[ni];
                v = v > 0.0f ? v : v * NEG_SLOPE;
                out[(size_t)row * OUT_D + col] = v;
            }
        }
    }
}

// ---------- launch ----------
extern "C" void kernel_launch(void* const* d_in, const int* in_sizes, int n_in,
                              void* d_out, int out_size, void* d_ws, size_t ws_size,
                              hipStream_t stream) {
    const float* x    = (const float*)d_in[0];
    const float* w    = (const float*)d_in[1];
    const float* bias = (const float*)d_in[2];
    const int*   rows = (const int*)d_in[3];
    const int*   cols = (const int*)d_in[4];
    const int nnz = in_sizes[1];
    float* out = (float*)d_out;

    const size_t NW = (size_t)IN_D * OUT_D;
    // ws: cnt 128 KB (pad 1 MiB) | bucket 48 MiB | Wt 32 MiB | Xb 32 MiB = 113 MiB
    unsigned*        cnt    = (unsigned*)d_ws;
    uint2*           bucket = (uint2*)((char*)d_ws + (1u << 20));
    unsigned short*  Wt     = (unsigned short*)((char*)d_ws + (1u << 20)
                                  + (size_t)NSEG * OUT_D * SEGCAP * 8);
    unsigned short*  Xb     = (unsigned short*)((char*)Wt + NW * 2);

    hipMemsetAsync(cnt, 0, (size_t)NSEG * OUT_D * sizeof(unsigned), stream);
    bucketcvt_kernel<<<4096, 256, 0, stream>>>(rows, cols, w, cnt, bucket, nnz,
                                               (const float4*)x, (ushort4*)Xb,
                                               (int)((size_t)BATCH * IN_D / 4));
    coldedup_kernel<<<OUT_D, 256, 0, stream>>>(bucket, cnt, Wt);

    dim3 grid(OUT_D / BN, BATCH / BM);
    gemm_kernel<<<grid, 512, 0, stream>>>(Xb, Wt, bias, out);
}